// Round 8
// baseline (9024.936 us; speedup 1.0000x reference)
//
#include <hip/hip_runtime.h>
#include <hip/hip_bf16.h>

// B=128, T=256, V=50000, D=300, H=300. 256 sample-rows (0..127 = s1, 128..255 = s2).
// MFMA bf16 pipeline; time-chunked (TC=32) xp + streaming-weight MFMA scan using a
// VGPR-free global_load_lds weight ring, asm ds_read (no compiler vmcnt drains),
// counted vmcnt, raw s_barrier.

typedef unsigned short u16;
typedef float fx4 __attribute__((ext_vector_type(4)));
typedef short s16x8 __attribute__((ext_vector_type(8)));

__device__ __forceinline__ float us2f(u16 u){
  unsigned int x = ((unsigned int)u) << 16;
  float f; __builtin_memcpy(&f, &x, 4); return f;
}
__device__ __forceinline__ u16 f2us(float f){
  unsigned int x; __builtin_memcpy(&x, &f, 4);
  unsigned int r = x + 0x7fffu + ((x >> 16) & 1u);
  return (u16)(r >> 16);
}
__device__ __forceinline__ float sigmf(float x){ return 1.0f/(1.0f + __expf(-x)); }
__device__ __forceinline__ float tanhfast(float x){ return 1.0f - 2.0f/(__expf(2.0f*x) + 1.0f); }

// ---------------- embedding gather -> p bf16 [65536][300] ----------------
__global__ __launch_bounds__(256) void k_embed(const int* __restrict__ s1, const int* __restrict__ s2,
                                               const float* __restrict__ emb, u16* __restrict__ p)
{
  int id = blockIdx.x*256 + threadIdx.x;
  if (id >= 65536*75) return;
  int row = id / 75;
  int c4 = (id - row*75) * 4;
  int tok = (row < 32768) ? s1[row] : s2[row - 32768];
  float4 v = *(const float4*)(emb + (size_t)tok*300 + c4);
  ushort4 o; o.x=f2us(v.x); o.y=f2us(v.y); o.z=f2us(v.z); o.w=f2us(v.w);
  *(ushort4*)(p + (size_t)row*300 + c4) = o;
}

// ---------------- f32 -> bf16 convert ----------------
__global__ __launch_bounds__(256) void k_cvt(const float* __restrict__ in, u16* __restrict__ out, int n)
{
  int id = blockIdx.x*256 + threadIdx.x;
  if (id < n) out[id] = f2us(in[id]);
}

// ---------------- pack Whh [1200][300] f32 into MFMA B-fragment stream ----------------
__global__ __launch_bounds__(256) void k_pack(const float* __restrict__ W, u16* __restrict__ pack)
{
  int id = blockIdx.x*256 + threadIdx.x;       // 51200 total
  if (id >= 51200) return;
  const int lane = id & 63;
  const int kt2 = (id >> 6) % 10;
  const int nt2 = id / 640;
  const int n = nt2*16 + (lane & 15);
  u16 tmp[8];
#pragma unroll
  for (int j = 0; j < 8; ++j){
    const int k = kt2*32 + (lane >> 4)*8 + j;
    tmp[j] = (n < 1200 && k < 300) ? f2us(W[(size_t)n*300 + k]) : (u16)0;
  }
  *(s16x8*)(pack + (size_t)id*8) = *(const s16x8*)tmp;
}

// ---------------- MFMA GEMM: xp chunk ----------------
__global__ __launch_bounds__(256) void k_mm_xpc(
    const u16* __restrict__ A,
    const u16* __restrict__ WFb, const u16* __restrict__ WBb,
    const float* __restrict__ bF1, const float* __restrict__ bF2,
    const float* __restrict__ bB1, const float* __restrict__ bB2,
    const int* __restrict__ l1, const int* __restrict__ l2,
    u16* __restrict__ xp, int c)
{
  const int dir = blockIdx.z;
  const u16* Bw = dir ? WBb : WFb;
  const float* b1 = dir ? bB1 : bF1;
  const float* b2 = dir ? bB2 : bF2;
  u16* xpd = xp + (size_t)dir*9830400;
  __shared__ u16 As[128][40];
  __shared__ u16 Bs[128][40];
  const int tid = threadIdx.x;
  const int m0 = blockIdx.y << 7;
  const int n0 = blockIdx.x << 7;
  const int srow0 = tid >> 2;
  const int kcol = (tid & 3) << 3;
  int src[2];
#pragma unroll
  for (int p = 0; p < 2; ++p){
    const int row = srow0 + (p << 6);
    const int ml = m0 + row;
    const int r = ml >> 5, tl = ml & 31;
    const int L = (r < 128) ? l1[r] : l2[r-128];
    const int tg = (c << 5) + tl;
    const int s = dir ? ((tg < L) ? (L-1-tg) : tg) : tg;
    src[p] = r*256 + s;
  }
  const int wv = tid >> 6;
  const int wm = (wv >> 1) << 6, wn = (wv & 1) << 6;
  const int lq = (tid >> 4) & 3;
  const int lr = tid & 15;
  fx4 acc[4][4];
#pragma unroll
  for (int i = 0; i < 4; ++i)
#pragma unroll
    for (int j = 0; j < 4; ++j) acc[i][j] = (fx4){0.f,0.f,0.f,0.f};

  for (int kt = 0; kt < 10; ++kt){
    const int k = (kt << 5) + kcol;
#pragma unroll
    for (int p = 0; p < 2; ++p){
      u16 tmp[8];
      const u16* ap = A + (size_t)src[p]*300 + k;
      if (k + 8 <= 300){
        *(ushort4*)&tmp[0] = *(const ushort4*)ap;
        *(ushort4*)&tmp[4] = *(const ushort4*)(ap + 4);
      } else {
#pragma unroll
        for (int j = 0; j < 8; ++j) tmp[j] = (k + j < 300) ? ap[j] : (u16)0;
      }
      *(s16x8*)&As[srow0 + (p << 6)][kcol] = *(const s16x8*)tmp;

      const int n = n0 + srow0 + (p << 6);
      u16 tmb[8] = {0,0,0,0,0,0,0,0};
      if (n < 1200){
        const u16* bp = Bw + (size_t)n*300 + k;
        if (k + 8 <= 300){
          *(ushort4*)&tmb[0] = *(const ushort4*)bp;
          *(ushort4*)&tmb[4] = *(const ushort4*)(bp + 4);
        } else {
#pragma unroll
          for (int j = 0; j < 8; ++j) tmb[j] = (k + j < 300) ? bp[j] : (u16)0;
        }
      }
      *(s16x8*)&Bs[srow0 + (p << 6)][kcol] = *(const s16x8*)tmb;
    }
    __syncthreads();
    s16x8 af[4], bf[4];
#pragma unroll
    for (int mi = 0; mi < 4; ++mi) af[mi] = *(const s16x8*)&As[wm + mi*16 + lr][lq << 3];
#pragma unroll
    for (int ni = 0; ni < 4; ++ni) bf[ni] = *(const s16x8*)&Bs[wn + ni*16 + lr][lq << 3];
#pragma unroll
    for (int mi = 0; mi < 4; ++mi)
#pragma unroll
      for (int ni = 0; ni < 4; ++ni)
        acc[mi][ni] = __builtin_amdgcn_mfma_f32_16x16x32_bf16(af[mi], bf[ni], acc[mi][ni], 0, 0, 0);
    __syncthreads();
  }
#pragma unroll
  for (int ni = 0; ni < 4; ++ni){
    const int n = n0 + wn + ni*16 + lr;
    if (n < 1200){
      const float bias = b1[n] + b2[n];
#pragma unroll
      for (int mi = 0; mi < 4; ++mi){
        const int m = m0 + wm + mi*16 + (lq << 2);
#pragma unroll
        for (int reg = 0; reg < 4; ++reg)
          xpd[(size_t)(m + reg)*1200 + n] = f2us(acc[mi][ni][reg] + bias);
      }
    }
  }
}

// ---------------- MFMA GEMM: S = u1 @ u2^T per b ----------------
__global__ __launch_bounds__(256) void k_mm_s(const u16* __restrict__ U, float* __restrict__ S)
{
  __shared__ u16 As[128][40];
  __shared__ u16 Bs[128][40];
  const int tid = threadIdx.x;
  const int bz = blockIdx.z;
  const u16* Ap = U + (size_t)bz*153600;
  const u16* Bp = U + (size_t)(128+bz)*153600;
  float* C = S + (size_t)bz*65536;
  const int m0 = blockIdx.y << 7;
  const int n0 = blockIdx.x << 7;
  const int srow0 = tid >> 2;
  const int kcol = (tid & 3) << 3;
  const int wv = tid >> 6;
  const int wm = (wv >> 1) << 6, wn = (wv & 1) << 6;
  const int lq = (tid >> 4) & 3;
  const int lr = tid & 15;
  fx4 acc[4][4];
#pragma unroll
  for (int i = 0; i < 4; ++i)
#pragma unroll
    for (int j = 0; j < 4; ++j) acc[i][j] = (fx4){0.f,0.f,0.f,0.f};

  for (int kt = 0; kt < 19; ++kt){
    const int k = (kt << 5) + kcol;
#pragma unroll
    for (int p = 0; p < 2; ++p){
      const int row = srow0 + (p << 6);
      u16 tma[8] = {0,0,0,0,0,0,0,0};
      u16 tmb[8] = {0,0,0,0,0,0,0,0};
      if (k + 8 <= 600){
        *(s16x8*)tma = *(const s16x8*)(Ap + (size_t)(m0 + row)*600 + k);
        *(s16x8*)tmb = *(const s16x8*)(Bp + (size_t)(n0 + row)*600 + k);
      }
      *(s16x8*)&As[row][kcol] = *(const s16x8*)tma;
      *(s16x8*)&Bs[row][kcol] = *(const s16x8*)tmb;
    }
    __syncthreads();
    s16x8 af[4], bf[4];
#pragma unroll
    for (int mi = 0; mi < 4; ++mi) af[mi] = *(const s16x8*)&As[wm + mi*16 + lr][lq << 3];
#pragma unroll
    for (int ni = 0; ni < 4; ++ni) bf[ni] = *(const s16x8*)&Bs[wn + ni*16 + lr][lq << 3];
#pragma unroll
    for (int mi = 0; mi < 4; ++mi)
#pragma unroll
      for (int ni = 0; ni < 4; ++ni)
        acc[mi][ni] = __builtin_amdgcn_mfma_f32_16x16x32_bf16(af[mi], bf[ni], acc[mi][ni], 0, 0, 0);
    __syncthreads();
  }
#pragma unroll
  for (int mi = 0; mi < 4; ++mi){
    const int m = m0 + wm + mi*16 + (lq << 2);
#pragma unroll
    for (int ni = 0; ni < 4; ++ni){
      const int n = n0 + wn + ni*16 + lr;
#pragma unroll
      for (int reg = 0; reg < 4; ++reg)
        C[(size_t)(m + reg)*256 + n] = acc[mi][ni][reg];
    }
  }
}

// ---------------- MFMA GEMM: pc = relu([u,A,u-A,u*A] @ projW^T + projB) ----------------
// 19 off-tiles x 2 passes (segs {0,1}, {2,3}); tiles staged once; XCD-swizzled grid (1536).
__global__ __launch_bounds__(256) void k_mm_proj(
    const u16* __restrict__ U, const u16* __restrict__ ATT,
    const u16* __restrict__ Bw,                // projW bf16 [300][2400]
    const float* __restrict__ bias,
    u16* __restrict__ C)
{
  __shared__ u16 As0[128][40];
  __shared__ u16 As1[128][40];
  __shared__ u16 Bs0[128][40];
  __shared__ u16 Bs1[128][40];
  const int tid = threadIdx.x;
  const int id = ((int)(blockIdx.x & 7))*192 + ((int)blockIdx.x >> 3);  // bijective XCD swizzle
  const int mg = id / 3, nb = id - mg*3;
  const int m0 = mg << 7, n0 = nb << 7;
  const int srow0 = tid >> 2;
  const int kcol = (tid & 3) << 3;
  const int wv = tid >> 6;
  const int wm = (wv >> 1) << 6, wn = (wv & 1) << 6;
  const int lq = (tid >> 4) & 3;
  const int lr = tid & 15;
  fx4 acc[4][4];
#pragma unroll
  for (int i = 0; i < 4; ++i)
#pragma unroll
    for (int j = 0; j < 4; ++j) acc[i][j] = (fx4){0.f,0.f,0.f,0.f};

  for (int kt = 0; kt < 19; ++kt){
    const int off = (kt << 5) + kcol;
    const bool ok = (off < 600);               // 600 = 18*32 + 24; tail zeros
    // ---- pass A: seg0 = u, seg1 = a ----
#pragma unroll
    for (int p = 0; p < 2; ++p){
      const int row = srow0 + (p << 6);
      u16 u8[8] = {0,0,0,0,0,0,0,0};
      u16 a8[8] = {0,0,0,0,0,0,0,0};
      if (ok){
        *(s16x8*)u8 = *(const s16x8*)(U   + (size_t)(m0+row)*600 + off);
        *(s16x8*)a8 = *(const s16x8*)(ATT + (size_t)(m0+row)*600 + off);
      }
      *(s16x8*)&As0[row][kcol] = *(const s16x8*)u8;
      *(s16x8*)&As1[row][kcol] = *(const s16x8*)a8;
      const int n = n0 + row;
      u16 w0[8] = {0,0,0,0,0,0,0,0};
      u16 w1[8] = {0,0,0,0,0,0,0,0};
      if (n < 300 && ok){
        *(s16x8*)w0 = *(const s16x8*)(Bw + (size_t)n*2400 + off);
        *(s16x8*)w1 = *(const s16x8*)(Bw + (size_t)n*2400 + 600 + off);
      }
      *(s16x8*)&Bs0[row][kcol] = *(const s16x8*)w0;
      *(s16x8*)&Bs1[row][kcol] = *(const s16x8*)w1;
    }
    __syncthreads();
    {
      s16x8 af0[4], af1[4], bf0[4], bf1[4];
#pragma unroll
      for (int mi = 0; mi < 4; ++mi){
        af0[mi] = *(const s16x8*)&As0[wm + mi*16 + lr][lq << 3];
        af1[mi] = *(const s16x8*)&As1[wm + mi*16 + lr][lq << 3];
      }
#pragma unroll
      for (int ni = 0; ni < 4; ++ni){
        bf0[ni] = *(const s16x8*)&Bs0[wn + ni*16 + lr][lq << 3];
        bf1[ni] = *(const s16x8*)&Bs1[wn + ni*16 + lr][lq << 3];
      }
#pragma unroll
      for (int mi = 0; mi < 4; ++mi)
#pragma unroll
        for (int ni = 0; ni < 4; ++ni){
          acc[mi][ni] = __builtin_amdgcn_mfma_f32_16x16x32_bf16(af0[mi], bf0[ni], acc[mi][ni], 0, 0, 0);
          acc[mi][ni] = __builtin_amdgcn_mfma_f32_16x16x32_bf16(af1[mi], bf1[ni], acc[mi][ni], 0, 0, 0);
        }
    }
    __syncthreads();
    // ---- pass B: seg2 = u-a, seg3 = u*a ----
#pragma unroll
    for (int p = 0; p < 2; ++p){
      const int row = srow0 + (p << 6);
      u16 u8[8] = {0,0,0,0,0,0,0,0};
      u16 a8[8] = {0,0,0,0,0,0,0,0};
      if (ok){
        *(s16x8*)u8 = *(const s16x8*)(U   + (size_t)(m0+row)*600 + off);
        *(s16x8*)a8 = *(const s16x8*)(ATT + (size_t)(m0+row)*600 + off);
      }
      u16 d8[8], m8[8];
#pragma unroll
      for (int j = 0; j < 8; ++j){
        const float uf = us2f(u8[j]), af = us2f(a8[j]);
        d8[j] = f2us(uf - af);
        m8[j] = f2us(uf * af);
      }
      *(s16x8*)&As0[row][kcol] = *(const s16x8*)d8;
      *(s16x8*)&As1[row][kcol] = *(const s16x8*)m8;
      const int n = n0 + row;
      u16 w2[8] = {0,0,0,0,0,0,0,0};
      u16 w3[8] = {0,0,0,0,0,0,0,0};
      if (n < 300 && ok){
        *(s16x8*)w2 = *(const s16x8*)(Bw + (size_t)n*2400 + 1200 + off);
        *(s16x8*)w3 = *(const s16x8*)(Bw + (size_t)n*2400 + 1800 + off);
      }
      *(s16x8*)&Bs0[row][kcol] = *(const s16x8*)w2;
      *(s16x8*)&Bs1[row][kcol] = *(const s16x8*)w3;
    }
    __syncthreads();
    {
      s16x8 af0[4], af1[4], bf0[4], bf1[4];
#pragma unroll
      for (int mi = 0; mi < 4; ++mi){
        af0[mi] = *(const s16x8*)&As0[wm + mi*16 + lr][lq << 3];
        af1[mi] = *(const s16x8*)&As1[wm + mi*16 + lr][lq << 3];
      }
#pragma unroll
      for (int ni = 0; ni < 4; ++ni){
        bf0[ni] = *(const s16x8*)&Bs0[wn + ni*16 + lr][lq << 3];
        bf1[ni] = *(const s16x8*)&Bs1[wn + ni*16 + lr][lq << 3];
      }
#pragma unroll
      for (int mi = 0; mi < 4; ++mi)
#pragma unroll
        for (int ni = 0; ni < 4; ++ni){
          acc[mi][ni] = __builtin_amdgcn_mfma_f32_16x16x32_bf16(af0[mi], bf0[ni], acc[mi][ni], 0, 0, 0);
          acc[mi][ni] = __builtin_amdgcn_mfma_f32_16x16x32_bf16(af1[mi], bf1[ni], acc[mi][ni], 0, 0, 0);
        }
    }
    __syncthreads();
  }
#pragma unroll
  for (int ni = 0; ni < 4; ++ni){
    const int n = n0 + wn + ni*16 + lr;
    if (n < 300){
      const float bs = bias[n];
#pragma unroll
      for (int mi = 0; mi < 4; ++mi){
        const int m = m0 + wm + mi*16 + (lq << 2);
#pragma unroll
        for (int reg = 0; reg < 4; ++reg)
          C[(size_t)(m + reg)*300 + n] = f2us(fmaxf(acc[mi][ni][reg] + bs, 0.0f));
      }
    }
  }
}

// ---------------- MFMA streaming scan: asm ds_read + counted vmcnt + raw barriers ----------------
__global__ __launch_bounds__(512) void k_scan_mf(
    const u16* __restrict__ xp,
    const u16* __restrict__ packF, const u16* __restrict__ packB,
    const int* __restrict__ l1, const int* __restrict__ l2,
    u16* __restrict__ uo,
    u16* __restrict__ hG, float* __restrict__ cG,
    int c)
{
  __shared__ u16 h_s[16][328];
  __shared__ float c_s[8][304];
  __shared__ float gs[8][1200];
  __shared__ u16 xstage[8][1200];
  __shared__ u16 wring[8][2][5][512];
  __shared__ int L_s[8];
  const int bid = blockIdx.x;
  const int dir = bid & 1, sg = bid >> 1;
  const int r0 = sg << 3;
  const u16* pack = dir ? packB : packF;
  const u16* xpd = xp + (size_t)dir*9830400;
  const int tid = threadIdx.x;
  if (tid < 8) L_s[tid] = (r0 + tid < 128) ? l1[r0 + tid] : l2[r0 + tid - 128];
  for (int i = tid; i < 16*328; i += 512){
    const int q = i / 328, d = i - q*328;
    u16 v = 0;
    if (q < 8 && c > 0) v = hG[(size_t)(dir*256 + r0 + q)*328 + d];
    h_s[q][d] = v;
  }
  for (int i = tid; i < 8*304; i += 512){
    const int q = i / 304, d = i - q*304;
    c_s[q][d] = (c > 0) ? cG[(size_t)(dir*256 + r0 + q)*304 + d] : 0.0f;
  }
  const int w = tid >> 6, lane = tid & 63;
  const int lq = lane >> 4, lr = lane & 15;
  const int tile0 = w * 10;
  const u16* pw = pack + (size_t)tile0*5120;
  const unsigned wbase = (unsigned)(uintptr_t)&wring[w][0][0][0] + (unsigned)lane*16u;

  int xq[3], xc[3]; bool xv[3];
#pragma unroll
  for (int j = 0; j < 3; ++j){
    const int i = tid + (j << 9);
    xv[j] = (i < 1200);
    const int qq = (i < 1200) ? (i / 150) : 0;
    xq[j] = qq;
    xc[j] = (i - qq*150) * 8;
  }
#pragma unroll
  for (int j = 0; j < 3; ++j){
    if (xv[j]){
      s16x8 v = *(const s16x8*)(xpd + (size_t)((r0 + xq[j])*32 + 0)*1200 + xc[j]);
      *(s16x8*)&xstage[xq[j]][xc[j]] = v;
    }
  }
  __syncthreads();
  int Lmax = 0;
#pragma unroll
  for (int q = 0; q < 8; ++q) Lmax = max(Lmax, L_s[q]);
  const int t0 = c << 5;
  int nts = Lmax - t0; if (nts > 32) nts = 32;
  if (nts <= 0) return;

#define WISSUE(PH)                                                                       \
  {                                                                                      \
    const int buf_ = (PH) & 1, kt_ = (PH) >> 1, hh_ = (PH) & 1;                          \
    _Pragma("unroll")                                                                    \
    for (int nt2 = 0; nt2 < 5; ++nt2){                                                   \
      const u16* ga = pw + ((size_t)((hh_*5 + nt2)*10 + kt_))*512 + (size_t)lane*8;      \
      __builtin_amdgcn_global_load_lds(                                                  \
        (const __attribute__((address_space(1))) void*)ga,                               \
        (__attribute__((address_space(3))) void*)&wring[w][buf_][nt2][0], 16, 0, 0);     \
    }                                                                                    \
  }

  WISSUE(0)
  WISSUE(1)

  for (int tl = 0; tl < nts; ++tl){
    const int t = t0 + tl;
    const bool pf = (tl + 1 < nts);
    s16x8 xr0, xr1, xr2;
    if (pf){
      if (xv[0]) xr0 = *(const s16x8*)(xpd + (size_t)((r0 + xq[0])*32 + tl + 1)*1200 + xc[0]);
      if (xv[1]) xr1 = *(const s16x8*)(xpd + (size_t)((r0 + xq[1])*32 + tl + 1)*1200 + xc[1]);
      if (xv[2]) xr2 = *(const s16x8*)(xpd + (size_t)((r0 + xq[2])*32 + tl + 1)*1200 + xc[2]);
    }
    fx4 acc[10];
#pragma unroll
    for (int nt = 0; nt < 10; ++nt) acc[nt] = (fx4){0.f,0.f,0.f,0.f};

#pragma unroll
    for (int ph = 0; ph < 20; ++ph){
      const int kt = ph >> 1, hh = ph & 1, buf = ph & 1;
      asm volatile("s_waitcnt vmcnt(5)" ::: "memory");
      __builtin_amdgcn_sched_barrier(0);
      const unsigned ab = wbase + (unsigned)(buf*5)*1024u;
      s16x8 b0, b1, b2, b3, b4;
      asm volatile("ds_read_b128 %0, %1"             : "=v"(b0) : "v"(ab));
      asm volatile("ds_read_b128 %0, %1 offset:1024" : "=v"(b1) : "v"(ab));
      asm volatile("ds_read_b128 %0, %1 offset:2048" : "=v"(b2) : "v"(ab));
      asm volatile("ds_read_b128 %0, %1 offset:3072" : "=v"(b3) : "v"(ab));
      asm volatile("ds_read_b128 %0, %1 offset:4096" : "=v"(b4) : "v"(ab));
      const s16x8 a = *(const s16x8*)&h_s[lr][kt*32 + (lq << 3)];
      asm volatile("s_waitcnt lgkmcnt(0)" ::: "memory");
      __builtin_amdgcn_sched_barrier(0);
      acc[hh*5+0] = __builtin_amdgcn_mfma_f32_16x16x32_bf16(a, b0, acc[hh*5+0], 0, 0, 0);
      acc[hh*5+1] = __builtin_amdgcn_mfma_f32_16x16x32_bf16(a, b1, acc[hh*5+1], 0, 0, 0);
      acc[hh*5+2] = __builtin_amdgcn_mfma_f32_16x16x32_bf16(a, b2, acc[hh*5+2], 0, 0, 0);
      acc[hh*5+3] = __builtin_amdgcn_mfma_f32_16x16x32_bf16(a, b3, acc[hh*5+3], 0, 0, 0);
      acc[hh*5+4] = __builtin_amdgcn_mfma_f32_16x16x32_bf16(a, b4, acc[hh*5+4], 0, 0, 0);
      WISSUE((ph + 2) % 20)
    }
    // acc -> gs (valid output rows m<8)
    if (lq < 2){
#pragma unroll
      for (int nt = 0; nt < 10; ++nt){
        const int n = (tile0 + nt)*16 + lr;
        if (n < 1200){
#pragma unroll
          for (int reg = 0; reg < 4; ++reg)
            gs[(lq << 2) + reg][n] = acc[nt][reg];
        }
      }
    }
    asm volatile("s_waitcnt lgkmcnt(0)" ::: "memory");
    __builtin_amdgcn_sched_barrier(0);
    __builtin_amdgcn_s_barrier();
    // nonlinearity + state update + output (gate = gs + xstage)
#pragma unroll
    for (int j = 0; j < 5; ++j){
      const int u0 = tid + (j << 9);
      if (u0 < 2400){
        const int q = u0 / 300, d = u0 - q*300;
        const int L = L_s[q];
        if (t < L){
          const float gi = gs[q][d]       + us2f(xstage[q][d]);
          const float gf = gs[q][300 + d] + us2f(xstage[q][300 + d]);
          const float gg = gs[q][600 + d] + us2f(xstage[q][600 + d]);
          const float go = gs[q][900 + d] + us2f(xstage[q][900 + d]);
          const float cn = sigmf(gf)*c_s[q][d] + sigmf(gi)*tanhfast(gg);
          const float hn = sigmf(go)*tanhfast(cn);
          c_s[q][d] = cn;
          const u16 hb = f2us(hn);
          h_s[q][d] = hb;
          const int wpos = dir ? (L-1-t) : t;
          uo[(size_t)((r0 + q)*256 + wpos)*600 + dir*300 + d] = hb;
        }
      }
    }
    asm volatile("s_waitcnt lgkmcnt(0)" ::: "memory");
    __builtin_amdgcn_sched_barrier(0);
    __builtin_amdgcn_s_barrier();
    if (pf){
      if (xv[0]) *(s16x8*)&xstage[xq[0]][xc[0]] = xr0;
      if (xv[1]) *(s16x8*)&xstage[xq[1]][xc[1]] = xr1;
      if (xv[2]) *(s16x8*)&xstage[xq[2]][xc[2]] = xr2;
    }
  }
#undef WISSUE
  for (int i = tid; i < 8*328; i += 512){
    const int q = i / 328, d = i - q*328;
    hG[(size_t)(dir*256 + r0 + q)*328 + d] = h_s[q][d];
  }
  for (int i = tid; i < 8*304; i += 512){
    const int q = i / 304, d = i - q*304;
    cG[(size_t)(dir*256 + r0 + q)*304 + d] = c_s[q][d];
  }
}

// ---------------- softmax stats ----------------
__global__ __launch_bounds__(256) void k_row_stats(const float* __restrict__ S, const int* __restrict__ l2,
                                                   float* __restrict__ rmax, float* __restrict__ rinv)
{
  const int wid = threadIdx.x >> 6, lane = threadIdx.x & 63;
  const int row = blockIdx.x*4 + wid;
  const int b = row >> 8;
  const int L2b = l2[b];
  float4 v = *(const float4*)(S + (size_t)row*256 + lane*4);
  const int j = lane*4;
  float m = -INFINITY;
  if (j   < L2b) m = fmaxf(m, v.x);
  if (j+1 < L2b) m = fmaxf(m, v.y);
  if (j+2 < L2b) m = fmaxf(m, v.z);
  if (j+3 < L2b) m = fmaxf(m, v.w);
  for (int off = 32; off; off >>= 1) m = fmaxf(m, __shfl_xor(m, off));
  float s = 0.f;
  if (j   < L2b) s += __expf(v.x - m);
  if (j+1 < L2b) s += __expf(v.y - m);
  if (j+2 < L2b) s += __expf(v.z - m);
  if (j+3 < L2b) s += __expf(v.w - m);
  for (int off = 32; off; off >>= 1) s += __shfl_xor(s, off);
  if (lane == 0){ rmax[row] = m; rinv[row] = 1.0f/s; }
}

__global__ __launch_bounds__(256) void k_col_stats(const float* __restrict__ S, const int* __restrict__ l1,
                                                   float* __restrict__ cmax, float* __restrict__ cinv)
{
  const int b = blockIdx.x;
  const int j = threadIdx.x;
  const int L1b = l1[b];
  const float* Sb = S + (size_t)b*65536;
  float m = -INFINITY;
  for (int i = 0; i < L1b; ++i) m = fmaxf(m, Sb[(size_t)i*256 + j]);
  float s = 0.f;
  for (int i = 0; i < L1b; ++i) s += __expf(Sb[(size_t)i*256 + j] - m);
  cmax[b*256 + j] = m;
  cinv[b*256 + j] = 1.0f/s;
}

// ---------------- A1 = softmax_rows(S) @ u2 -> att bf16 ----------------
__global__ __launch_bounds__(256) void k_av_row(
    const float* __restrict__ S, const u16* __restrict__ U,
    const int* __restrict__ l1, const int* __restrict__ l2,
    const float* __restrict__ rmax, const float* __restrict__ rinv,
    u16* __restrict__ ATT)
{
  __shared__ float Ps[32][68];
  __shared__ float Us[32][68];
  const int tid = threadIdx.x;
  const int b = blockIdx.z;
  const int i0 = blockIdx.y << 6;
  const int d0 = blockIdx.x << 6;
  const int L1b = l1[b], L2b = l2[b];
  const float* Sb = S + (size_t)b*65536;
  const u16* u2 = U + (size_t)(128+b)*153600;
  const int tx = tid & 15, ty = tid >> 4;
  float acc[4][4];
#pragma unroll
  for (int i = 0; i < 4; ++i)
#pragma unroll
    for (int j = 0; j < 4; ++j) acc[i][j] = 0.0f;

  for (int kt = 0; kt < 8; ++kt){
    const int j0 = kt << 5;
#pragma unroll
    for (int q = 0; q < 2; ++q){
      const int f4 = tid + (q << 8);
      {
        const int row = f4 >> 3;
        const int c4 = (f4 & 7) << 2;
        const int i = i0 + row;
        float4 s4 = *(const float4*)(Sb + (size_t)i*256 + j0 + c4);
        const float rm = rmax[(b<<8) + i];
        const float ri = rinv[(b<<8) + i];
        const int jb = j0 + c4;
        Ps[c4  ][row] = (jb   < L2b) ? __expf(s4.x - rm)*ri : 0.0f;
        Ps[c4+1][row] = (jb+1 < L2b) ? __expf(s4.y - rm)*ri : 0.0f;
        Ps[c4+2][row] = (jb+2 < L2b) ? __expf(s4.z - rm)*ri : 0.0f;
        Ps[c4+3][row] = (jb+3 < L2b) ? __expf(s4.w - rm)*ri : 0.0f;
      }
      {
        const int row = f4 >> 4;
        const int c4 = (f4 & 15) << 2;
        const int d = d0 + c4;
        float4 v = make_float4(0.f,0.f,0.f,0.f);
        if (j0 + row < L2b){
          const u16* up = u2 + (size_t)(j0+row)*600 + d;
          if (d + 3 < 600){
            ushort4 t4 = *(const ushort4*)up;
            v.x=us2f(t4.x); v.y=us2f(t4.y); v.z=us2f(t4.z); v.w=us2f(t4.w);
          } else {
            if (d   < 600) v.x = us2f(up[0]);
            if (d+1 < 600) v.y = us2f(up[1]);
            if (d+2 < 600) v.z = us2f(up[2]);
          }
        }
        *(float4*)&Us[row][c4] = v;
      }
    }
    __syncthreads();
#pragma unroll
    for (int kk = 0; kk < 32; ++kk){
      float4 a = *(const float4*)&Ps[kk][ty<<2];
      float4 bb = *(const float4*)&Us[kk][tx<<2];
      float av[4] = {a.x,a.y,a.z,a.w};
      float bv[4] = {bb.x,bb.y,bb.z,bb.w};
#pragma unroll
      for (int ii = 0; ii < 4; ++ii)
#pragma unroll
        for (int jj = 0; jj < 4; ++jj)
          acc[ii][jj] = fmaf(av[ii], bv[jj], acc[ii][jj]);
    }
    __syncthreads();
  }
#pragma unroll
  for (int ii = 0; ii < 4; ++ii){
    const int i = i0 + (ty<<2) + ii;
#pragma unroll
    for (int jj = 0; jj < 4; ++jj){
      const int d = d0 + (tx<<2) + jj;
      if (d < 600)
        ATT[(size_t)b*153600 + (size_t)i*600 + d] = f2us((i < L1b) ? acc[ii][jj] : 0.0f);
    }
  }
}

// ---------------- A2 = softmax_cols(S)^T @ u1 -> att bf16 ----------------
__global__ __launch_bounds__(256) void k_av_col(
    const float* __restrict__ S, const u16* __restrict__ U,
    const int* __restrict__ l1, const int* __restrict__ l2,
    const float* __restrict__ cmax, const float* __restrict__ cinv,
    u16* __restrict__ ATT)
{
  __shared__ float Ps[32][68];
  __shared__ float Us[32][68];
  const int tid = threadIdx.x;
  const int b = blockIdx.z;
  const int j0v = blockIdx.y << 6;
  const int d0 = blockIdx.x << 6;
  const int L1b = l1[b], L2b = l2[b];
  const float* Sb = S + (size_t)b*65536;
  const u16* u1 = U + (size_t)b*153600;
  const int tx = tid & 15, ty = tid >> 4;
  float acc[4][4];
#pragma unroll
  for (int i = 0; i < 4; ++i)
#pragma unroll
    for (int j = 0; j < 4; ++j) acc[i][j] = 0.0f;

  for (int kt = 0; kt < 8; ++kt){
    const int i0k = kt << 5;
#pragma unroll
    for (int q = 0; q < 2; ++q){
      const int f4 = tid + (q << 8);
      const int row = f4 >> 4;
      const int c4 = (f4 & 15) << 2;
      {
        const int i = i0k + row;
        const int j = j0v + c4;
        float4 s4 = *(const float4*)(Sb + (size_t)i*256 + j);
        const bool iok = i < L1b;
        Ps[row][c4  ] = iok ? __expf(s4.x - cmax[(b<<8)+j  ])*cinv[(b<<8)+j  ] : 0.0f;
        Ps[row][c4+1] = iok ? __expf(s4.y - cmax[(b<<8)+j+1])*cinv[(b<<8)+j+1] : 0.0f;
        Ps[row][c4+2] = iok ? __expf(s4.z - cmax[(b<<8)+j+2])*cinv[(b<<8)+j+2] : 0.0f;
        Ps[row][c4+3] = iok ? __expf(s4.w - cmax[(b<<8)+j+3])*cinv[(b<<8)+j+3] : 0.0f;
      }
      {
        const int d = d0 + c4;
        float4 v = make_float4(0.f,0.f,0.f,0.f);
        if (i0k + row < L1b){
          const u16* up = u1 + (size_t)(i0k+row)*600 + d;
          if (d + 3 < 600){
            ushort4 t4 = *(const ushort4*)up;
            v.x=us2f(t4.x); v.y=us2f(t4.y); v.z=us2f(t4.z); v.w=us2f(t4.w);
          } else {
            if (d   < 600) v.x = us2f(up[0]);
            if (d+1 < 600) v.y = us2f(up[1]);
            if (d+2 < 600) v.z = us2f(up[2]);
          }
        }
        *(float4*)&Us[row][c4] = v;
      }
    }
    __syncthreads();
#pragma unroll
    for (int kk = 0; kk < 32; ++kk){
      float4 a = *(const float4*)&Ps[kk][ty<<2];
      float4 bb = *(const float4*)&Us[kk][tx<<2];
      float av[4] = {a.x,a.y,a.z,a.w};
      float bv[4] = {bb.x,bb.y,bb.z,bb.w};
#pragma unroll
      for (int ii = 0; ii < 4; ++ii)
#pragma unroll
        for (int jj = 0; jj < 4; ++jj)
          acc[ii][jj] = fmaf(av[ii], bv[jj], acc[ii][jj]);
    }
    __syncthreads();
  }
#pragma unroll
  for (int ii = 0; ii < 4; ++ii){
    const int j = j0v + (ty<<2) + ii;
#pragma unroll
    for (int jj = 0; jj < 4; ++jj){
      const int d = d0 + (tx<<2) + jj;
      if (d < 600)
        ATT[(size_t)(128+b)*153600 + (size_t)j*600 + d] = f2us((j < L2b) ? acc[ii][jj] : 0.0f);
    }
  }
}

// ---------------- masked max over time + feature build ----------------
__global__ __launch_bounds__(256) void k_maxfeat(const u16* __restrict__ y,
                                                 const int* __restrict__ l1, const int* __restrict__ l2,
                                                 float* __restrict__ feat)
{
  const int b = blockIdx.x;
  const int La = l1[b], Lb = l2[b];
  for (int c = threadIdx.x; c < 600; c += 256){
    float m1 = -INFINITY, m2 = -INFINITY;
    const u16* y1 = y + (size_t)b*153600 + c;
    for (int t = 0; t < La; ++t) m1 = fmaxf(m1, us2f(y1[(size_t)t*600]));
    const u16* y2 = y + (size_t)(128+b)*153600 + c;
    for (int t = 0; t < Lb; ++t) m2 = fmaxf(m2, us2f(y2[(size_t)t*600]));
    feat[(size_t)b*2400 + c]        = m1;
    feat[(size_t)b*2400 + 600 + c]  = m2;
    feat[(size_t)b*2400 + 1200 + c] = fabsf(m1 - m2);
    feat[(size_t)b*2400 + 1800 + c] = m1*m2;
  }
}

// ---------------- per-row MLP ----------------
__global__ __launch_bounds__(256) void k_rowgemm(const float* __restrict__ feat, const float* __restrict__ W,
                                                 const float* __restrict__ bias, float* __restrict__ out)
{
  const int b = blockIdx.x;
  __shared__ float ff[2400];
  for (int i = threadIdx.x; i < 2400; i += 256) ff[i] = feat[(size_t)b*2400 + i];
  __syncthreads();
  for (int n = threadIdx.x; n < 300; n += 256){
    const float* w = W + (size_t)n*2400;
    float acc = bias[n];
    for (int k = 0; k < 2400; k += 4){
      float4 wv = *(const float4*)(w + k);
      acc += ff[k]*wv.x + ff[k+1]*wv.y + ff[k+2]*wv.z + ff[k+3]*wv.w;
    }
    out[(size_t)b*300 + n] = fmaxf(acc, 0.0f);
  }
}

// ---------------- final ----------------
__global__ __launch_bounds__(192) void k_final(const float* __restrict__ h, const float* __restrict__ smW,
                                               const float* __restrict__ smB, float* __restrict__ out)
{
  const int b = blockIdx.x;
  const int n = threadIdx.x >> 6, lane = threadIdx.x & 63;
  float acc = 0.f;
  for (int k = lane; k < 300; k += 64) acc += h[(size_t)b*300 + k]*smW[(size_t)n*300 + k];
  for (int off = 32; off; off >>= 1) acc += __shfl_xor(acc, off);
  if (lane == 0) out[b*3 + n] = acc + smB[n];
}

extern "C" void kernel_launch(void* const* d_in, const int* in_sizes, int n_in,
                              void* d_out, int out_size, void* d_ws, size_t ws_size,
                              hipStream_t stream)
{
  (void)in_sizes; (void)n_in; (void)out_size;
  static const size_t OFF_P  = 0;
  static const size_t OFF_B  = 39321600;
  static const size_t OFF_U  = 78643200;
  static const size_t OFF_D  = 157286400;
  static const size_t OFF_WT = 235929600;
  static const size_t OFF_PJ = 238809600;
  static const size_t OFF_PK = 240249600;
  static const size_t OFF_ST = 243526400;
  static const size_t OFF_FE = 244050688;
  static const size_t OFF_HM = 245279488;
  static const size_t OFF_HC = 245433088;
  static const size_t WS_NEEDED = 246391552;
  if (ws_size < WS_NEEDED) return;

  const int* s1 = (const int*)d_in[0];
  const int* l1 = (const int*)d_in[1];
  const int* s2 = (const int*)d_in[2];
  const int* l2 = (const int*)d_in[3];
  const float* emb    = (const float*)d_in[4];
  const float* w1f_ih = (const float*)d_in[5];
  const float* w1f_hh = (const float*)d_in[6];
  const float* b1f_ih = (const float*)d_in[7];
  const float* b1f_hh = (const float*)d_in[8];
  const float* w1b_ih = (const float*)d_in[9];
  const float* w1b_hh = (const float*)d_in[10];
  const float* b1b_ih = (const float*)d_in[11];
  const float* b1b_hh = (const float*)d_in[12];
  const float* w2f_ih = (const float*)d_in[13];
  const float* w2f_hh = (const float*)d_in[14];
  const float* b2f_ih = (const float*)d_in[15];
  const float* b2f_hh = (const float*)d_in[16];
  const float* w2b_ih = (const float*)d_in[17];
  const float* w2b_hh = (const float*)d_in[18];
  const float* b2b_ih = (const float*)d_in[19];
  const float* b2b_hh = (const float*)d_in[20];
  const float* projW  = (const float*)d_in[21];
  const float* projB  = (const float*)d_in[22];
  const float* mlpW   = (const float*)d_in[23];
  const float* mlpB   = (const float*)d_in[24];
  const float* smW    = (const float*)d_in[25];
  const float* smB    = (const float*)d_in[26];

  char* ws = (char*)d_ws;
  u16*   p    = (u16*)(ws + OFF_P);
  u16*   xp1  = (u16*)(ws + OFF_B);
  float* Smat = (float*)(ws + OFF_B);
  u16*   pc   = (u16*)(ws + OFF_B);
  u16*   uu   = (u16*)(ws + OFF_U);
  u16*   att  = (u16*)(ws + OFF_D);
  u16*   xp2  = (u16*)(ws + OFF_D);
  u16*   wih  = (u16*)(ws + OFF_WT);
  u16*   pjw  = (u16*)(ws + OFF_PJ);
  u16*   pk   = (u16*)(ws + OFF_PK);
  float* st   = (float*)(ws + OFF_ST);
  float* feat = (float*)(ws + OFF_FE);
  float* hml  = (float*)(ws + OFF_HM);
  u16*   hG   = (u16*)(ws + OFF_HC);
  float* cG   = (float*)(ws + OFF_HC + 335872);

  k_embed<<<19200, 256, 0, stream>>>(s1, s2, emb, p);
  k_cvt<<<1407, 256, 0, stream>>>(w1f_ih, wih,           360000);
  k_cvt<<<1407, 256, 0, stream>>>(w1b_ih, wih + 360000,  360000);
  k_cvt<<<1407, 256, 0, stream>>>(w2f_ih, wih + 720000,  360000);
  k_cvt<<<1407, 256, 0, stream>>>(w2b_ih, wih + 1080000, 360000);
  k_cvt<<<2813, 256, 0, stream>>>(projW,  pjw,           720000);
  k_pack<<<200, 256, 0, stream>>>(w1f_hh, pk);
  k_pack<<<200, 256, 0, stream>>>(w1b_hh, pk + 409600);
  k_pack<<<200, 256, 0, stream>>>(w2f_hh, pk + 819200);
  k_pack<<<200, 256, 0, stream>>>(w2b_hh, pk + 1228800);

  const dim3 gxp(10, 64, 2);
  for (int c = 0; c < 8; ++c){
    k_mm_xpc<<<gxp, 256, 0, stream>>>(p, wih, wih + 360000, b1f_ih, b1f_hh, b1b_ih, b1b_hh,
                                      l1, l2, xp1, c);
    k_scan_mf<<<64, 512, 0, stream>>>(xp1, pk, pk + 409600, l1, l2, uu, hG, cG, c);
  }

  k_mm_s<<<dim3(2,2,128), 256, 0, stream>>>(uu, Smat);
  k_row_stats<<<8192, 256, 0, stream>>>(Smat, l2, st, st + 32768);
  k_col_stats<<<128, 256, 0, stream>>>(Smat, l1, st + 65536, st + 98304);
  k_av_row<<<dim3(10,4,128), 256, 0, stream>>>(Smat, uu, l1, l2, st, st + 32768, att);
  k_av_col<<<dim3(10,4,128), 256, 0, stream>>>(Smat, uu, l1, l2, st + 65536, st + 98304, att);

  k_mm_proj<<<1536, 256, 0, stream>>>(uu, att, pjw, projB, pc);

  for (int c = 0; c < 8; ++c){
    k_mm_xpc<<<gxp, 256, 0, stream>>>(pc, wih + 720000, wih + 1080000, b2f_ih, b2f_hh, b2b_ih, b2b_hh,
                                      l1, l2, xp2, c);
    k_scan_mf<<<64, 512, 0, stream>>>(xp2, pk + 819200, pk + 1228800, l1, l2, uu, hG, cG, c);
  }

  k_maxfeat<<<128, 256, 0, stream>>>(uu, l1, l2, feat);
  k_rowgemm<<<128, 256, 0, stream>>>(feat, mlpW, mlpB, hml);
  k_final<<<128, 192, 0, stream>>>(hml, smW, smB, (float*)d_out);
}